// Round 9
// baseline (510.188 us; speedup 1.0000x reference)
//
#include <hip/hip_runtime.h>
#include <hip/hip_cooperative_groups.h>
#include <stdint.h>

namespace cg = cooperative_groups;

typedef unsigned short u16;
typedef unsigned int u32;

#define N_NODES 2708
#define IN_C    2048
#define OUT_C   512
#define MP      2816   // padded node count (multiple of 128)
#define KP      2816   // padded K for gemm2 (= MP)

using floatx4 = __attribute__((ext_vector_type(4))) float;
using short8  = __attribute__((ext_vector_type(8))) short;

// ---- workspace layout (43.9 MB total; 48.2 MB proven available in R0-R2) ----
constexpr size_t XB_OFF = 0;
constexpr size_t XB_SZ  = (size_t)MP * IN_C * 2;      // 11,534,336
constexpr size_t WB_OFF = XB_OFF + XB_SZ;
constexpr size_t WB_SZ  = (size_t)OUT_C * IN_C * 2;   //  2,097,152
constexpr size_t HT_OFF = WB_OFF + WB_SZ;
constexpr size_t HT_SZ  = (size_t)OUT_C * MP * 2;     //  2,883,584
constexpr size_t AC_OFF = HT_OFF + HT_SZ;             // 16,515,072
constexpr size_t AC_SZ  = (size_t)MP * KP * 2;        // 15,859,712
constexpr size_t P_OFF  = AC_OFF + AC_SZ;             // 32,374,784
constexpr size_t P_SZ   = (size_t)2 * OUT_C * MP * 4; // 11,534,336 (P1/P2 share)

constexpr int ZF4 = (int)(AC_SZ / 16);                // 991,232
constexpr int GEMM_BLK = 352;                         // 8 bn x 22 bm x 2 ks

static __device__ __forceinline__ u16 f2bf(float f) {
  union { float f; u32 u; } v; v.f = f;
  u32 r = v.u + 0x7fffu + ((v.u >> 16) & 1u);  // RNE
  return (u16)(r >> 16);
}
static __device__ __forceinline__ u32 cvt2(u32 w) {
  float lo = (float)(w & 0xffffu), hi = (float)(w >> 16);
  return (u32)f2bf(lo) | ((u32)f2bf(hi) << 16);
}

// ======== shared phase bodies (used by mega-kernel AND fallback kernels) ====

static __device__ __forceinline__ void prep_x_body(int i, const float* __restrict__ x,
                                                   u16* __restrict__ xb) {
  const int row = i >> 8, col = (i & 255) * 8;   // IN_C/8 = 256 chunks/row
  union { u16 u[8]; uint4 v; } o;
  if (row < N_NODES) {
    float4 v0 = *(const float4*)&x[(size_t)row * IN_C + col];
    float4 v1 = *(const float4*)&x[(size_t)row * IN_C + col + 4];
    o.u[0]=f2bf(v0.x); o.u[1]=f2bf(v0.y); o.u[2]=f2bf(v0.z); o.u[3]=f2bf(v0.w);
    o.u[4]=f2bf(v1.x); o.u[5]=f2bf(v1.y); o.u[6]=f2bf(v1.z); o.u[7]=f2bf(v1.w);
  } else {
    o.v = make_uint4(0, 0, 0, 0);
  }
  *(uint4*)&xb[(size_t)row * IN_C + col] = o.v;
}

static __device__ __forceinline__ void prep_w_body(int i, const float* __restrict__ w,
                                                   u16* __restrict__ wb) {
  const int idx = i * 8;
  float4 v0 = *(const float4*)&w[idx];
  float4 v1 = *(const float4*)&w[idx + 4];
  union { u16 u[8]; uint4 v; } o;
  o.u[0]=f2bf(v0.x); o.u[1]=f2bf(v0.y); o.u[2]=f2bf(v0.z); o.u[3]=f2bf(v0.w);
  o.u[4]=f2bf(v1.x); o.u[5]=f2bf(v1.y); o.u[6]=f2bf(v1.z); o.u[7]=f2bf(v1.w);
  *(uint4*)&wb[idx] = o.v;
}

static __device__ __forceinline__ void red1_body(int i8, const float* __restrict__ P1,
                                                 const float* __restrict__ bias,
                                                 u16* __restrict__ hT) {
  int n = i8 / (MP / 8);
  int m0 = (i8 - n * (MP / 8)) * 8;
  float bv = bias[n];
  const float* p0 = &P1[(size_t)n * MP + m0];
  const float* p1 = p0 + (size_t)OUT_C * MP;
  float4 a0 = *(const float4*)p0, a1 = *(const float4*)(p0 + 4);
  float4 b0 = *(const float4*)p1, b1 = *(const float4*)(p1 + 4);
  union { u16 u[8]; uint4 v; } o;
  o.u[0]=f2bf(a0.x+b0.x+bv); o.u[1]=f2bf(a0.y+b0.y+bv);
  o.u[2]=f2bf(a0.z+b0.z+bv); o.u[3]=f2bf(a0.w+b0.w+bv);
  o.u[4]=f2bf(a1.x+b1.x+bv); o.u[5]=f2bf(a1.y+b1.y+bv);
  o.u[6]=f2bf(a1.z+b1.z+bv); o.u[7]=f2bf(a1.w+b1.w+bv);
  *(uint4*)&hT[(size_t)n * MP + m0] = o.v;
}

static __device__ __forceinline__ void red2_body(int i, const float* __restrict__ P2,
                                                 float* __restrict__ out) {
  size_t o = (size_t)i * 4;
  float4 a = *(const float4*)&P2[o];
  float4 b = *(const float4*)&P2[(size_t)MP * OUT_C + o];
  *(float4*)&out[o] = make_float4(a.x + b.x, a.y + b.y, a.z + b.z, a.w + b.w);
}

// ---- GEMM phase: P[ks] partial of C[m][n] = sum_k A[m][k]*B[n][k], bf16.
// BM=128 BN=64 BK=64, KS=2, 4 waves 2x2 (R8-proven). Virtual grid 352
// (blockIdx.x < 352), XCD-bijective swizzle with cpx=44. T4 3-buf/2-ahead
// counted-vmcnt pipeline, T2 both-sides swizzle, T5 setprio.
// EPI=0: dst = P1 f32 [KS][OUT_C][MP]; EPI=1: dst = P2 f32 [KS][MP][OUT_C].
template<int LDK, int NKI, int EPI>
static __device__ __forceinline__ void gemm_phase(
    const u16* __restrict__ A, const u16* __restrict__ B,
    float* __restrict__ dst, u16* lAp, u16* lBp) {
  const int tid = threadIdx.x, lane = tid & 63, wid = tid >> 6;

  const int orig = blockIdx.x;                  // < 352
  const int swz = (orig & 7) * 44 + (orig >> 3);
  const int bn = swz & 7;
  const int rest = swz >> 3;                    // 0..43
  const int ks = (rest >= 22) ? 1 : 0;
  const int bm = rest - ks * 22;
  const int bmr = bm * 128, bnr = bn * 64;
  const long k0b = (long)ks * LDK;              // K byte-offset (LDK/2 elems * 2B)

  const int wr = wid >> 1, wc = wid & 1;

  const int swzl = ((lane & 7) ^ ((lane >> 3) & 7)) * 16;
  const char* ag[4];
  const char* bg[2];
#pragma unroll
  for (int j = 0; j < 4; ++j) {
    int c = wid + 4 * j, row = 8 * c + (lane >> 3);
    ag[j] = (const char*)A + (size_t)(bmr + row) * (LDK * 2) + k0b + swzl;
  }
#pragma unroll
  for (int j = 0; j < 2; ++j) {
    int c = wid + 4 * j, row = 8 * c + (lane >> 3);
    bg[j] = (const char*)B + (size_t)(bnr + row) * (LDK * 2) + k0b + swzl;
  }

  // 6 global_load_lds per thread per STAGE (4 A + 2 B) -> vmcnt units of 6
#define STAGE(bb, tt) do {                                                         \
  _Pragma("unroll")                                                                \
  for (int j = 0; j < 4; ++j)                                                      \
    __builtin_amdgcn_global_load_lds(                                              \
      (const __attribute__((address_space(1))) u32*)(ag[j] + (size_t)(tt) * 128),  \
      (__attribute__((address_space(3))) u32*)&lAp[(bb) * 8192 + (wid + 4*j)*512], \
      16, 0, 0);                                                                   \
  _Pragma("unroll")                                                                \
  for (int j = 0; j < 2; ++j)                                                      \
    __builtin_amdgcn_global_load_lds(                                              \
      (const __attribute__((address_space(1))) u32*)(bg[j] + (size_t)(tt) * 128),  \
      (__attribute__((address_space(3))) u32*)&lBp[(bb) * 4096 + (wid + 4*j)*512], \
      16, 0, 0);                                                                   \
} while (0)

  floatx4 acc[4][2] = {};

  STAGE(0, 0);
  if (NKI > 1) STAGE(1, 1);
  int cur = 0;
  for (int t = 0; t < NKI; ++t) {
    if (t + 1 < NKI) asm volatile("s_waitcnt vmcnt(6)" ::: "memory");
    else             asm volatile("s_waitcnt vmcnt(0)" ::: "memory");
    __builtin_amdgcn_s_barrier();
    asm volatile("" ::: "memory");
    if (t + 2 < NKI) {
      int nb = cur + 2; if (nb >= 3) nb -= 3;
      STAGE(nb, t + 2);
    }
    const u16* pA = lAp + cur * 8192;
    const u16* pB = lBp + cur * 4096;
    short8 af[4][2], bf[2][2];
#pragma unroll
    for (int mi = 0; mi < 4; ++mi)
#pragma unroll
      for (int kk = 0; kk < 2; ++kk) {
        const int row = wr * 64 + mi * 16 + (lane & 15);
        const int col8 = ((kk * 4 + (lane >> 4)) ^ (lane & 7)) * 8;
        af[mi][kk] = *(const short8*)&pA[row * 64 + col8];
      }
#pragma unroll
    for (int ni = 0; ni < 2; ++ni)
#pragma unroll
      for (int kk = 0; kk < 2; ++kk) {
        const int row = wc * 32 + ni * 16 + (lane & 15);
        const int col8 = ((kk * 4 + (lane >> 4)) ^ (lane & 7)) * 8;
        bf[ni][kk] = *(const short8*)&pB[row * 64 + col8];
      }
    __builtin_amdgcn_s_setprio(1);
#pragma unroll
    for (int kk = 0; kk < 2; ++kk)
#pragma unroll
      for (int mi = 0; mi < 4; ++mi)
#pragma unroll
        for (int ni = 0; ni < 2; ++ni)
          acc[mi][ni] = __builtin_amdgcn_mfma_f32_16x16x32_bf16(af[mi][kk], bf[ni][kk], acc[mi][ni], 0, 0, 0);
    __builtin_amdgcn_s_setprio(0);
    ++cur; if (cur >= 3) cur -= 3;
  }
#undef STAGE

  const int lr = (lane >> 4) * 4, lc = lane & 15;
  if (EPI == 0) {
#pragma unroll
    for (int ni = 0; ni < 2; ++ni) {
      const int n = bnr + wc * 32 + ni * 16 + lc;
#pragma unroll
      for (int mi = 0; mi < 4; ++mi) {
        const int m0 = bmr + wr * 64 + mi * 16 + lr;
        *(floatx4*)&dst[((size_t)ks * OUT_C + n) * MP + m0] = acc[mi][ni];
      }
    }
  } else {
#pragma unroll
    for (int mi = 0; mi < 4; ++mi)
#pragma unroll
      for (int j = 0; j < 4; ++j) {
        const int m = bmr + wr * 64 + mi * 16 + lr + j;
#pragma unroll
        for (int ni = 0; ni < 2; ++ni) {
          const int n = bnr + wc * 32 + ni * 16 + lc;
          dst[((size_t)ks * MP + m) * OUT_C + n] = acc[mi][ni][j];
        }
      }
  }
}

// ======== cooperative mega-kernel: all 7 phases, 6 grid syncs ========
__global__ __launch_bounds__(256, 2) void k_mega(
    const float* __restrict__ x, const int* __restrict__ ei,
    const float* __restrict__ w, const float* __restrict__ bias,
    u16* __restrict__ xb, u16* __restrict__ wb, u16* __restrict__ hT,
    u16* __restrict__ Ac, float* __restrict__ P, float* __restrict__ out,
    int E) {
  __shared__ u16 lA[3][128 * 64];
  __shared__ u16 lB[3][64 * 64];
  cg::grid_group grid = cg::this_grid();
  const int gtid = blockIdx.x * 256 + threadIdx.x;
  const int NT = (int)gridDim.x * 256;           // 131072

  // P0: x->bf16 (padded), w->bf16, zero Ac
  for (int i = gtid; i < MP * IN_C / 8; i += NT) prep_x_body(i, x, xb);
  for (int i = gtid; i < OUT_C * IN_C / 8; i += NT) prep_w_body(i, w, wb);
  {
    float4* zac = (float4*)Ac;
    const float4 z = make_float4(0.f, 0.f, 0.f, 0.f);
    for (int i = gtid; i < ZF4; i += NT) zac[i] = z;
  }
  grid.sync();
  // P1: edge counts (u16 halfword atomics)
  {
    u32* Ac32 = (u32*)Ac;
    for (int e = gtid; e < E; e += NT) {
      int src = ei[e];
      int dst = ei[E + e];
      u32 idx = (u32)dst * KP + (u32)src;
      atomicAdd(&Ac32[idx >> 1], 1u << ((idx & 1) * 16));
    }
  }
  grid.sync();
  // P2: counts -> bf16 in place
  {
    uint4* A4 = (uint4*)Ac;
    for (int i = gtid; i < ZF4; i += NT) {
      uint4 v = A4[i];
      A4[i] = make_uint4(cvt2(v.x), cvt2(v.y), cvt2(v.z), cvt2(v.w));
    }
  }
  grid.sync();
  // P3: GEMM1 partials P1[ks][n][m]
  if (blockIdx.x < GEMM_BLK)
    gemm_phase<IN_C, IN_C / 2 / 64, 0>(xb, wb, P, &lA[0][0], &lB[0][0]);
  grid.sync();
  // P4: reduce + bias -> hT bf16
  for (int i = gtid; i < OUT_C * MP / 8; i += NT) red1_body(i, P, bias, hT);
  grid.sync();
  // P5: GEMM2 partials P2[ks][m][n]
  if (blockIdx.x < GEMM_BLK)
    gemm_phase<KP, KP / 2 / 64, 1>(Ac, hT, P, &lA[0][0], &lB[0][0]);
  grid.sync();
  // P6: reduce -> out
  for (int i = gtid; i < N_NODES * OUT_C / 4; i += NT) red2_body(i, P, out);
}

// ======== fallback kernels (R8 path, used if coop launch unavailable) ========
constexpr int XBLK = MP * IN_C / 8 / 256;
constexpr int WBLK = OUT_C * IN_C / 8 / 256;
constexpr int ZBLK = ZF4 / 256;
constexpr int PREP_BLK = XBLK + WBLK + ZBLK;

__global__ void k_prep(const float* __restrict__ x, const float* __restrict__ w,
                       u16* __restrict__ xb, u16* __restrict__ wb,
                       float4* __restrict__ zac) {
  const int b = blockIdx.x, tid = threadIdx.x;
  if (b < XBLK) {
    prep_x_body(b * 256 + tid, x, xb);
  } else if (b < XBLK + WBLK) {
    prep_w_body((b - XBLK) * 256 + tid, w, wb);
  } else {
    zac[(b - XBLK - WBLK) * 256 + tid] = make_float4(0.f, 0.f, 0.f, 0.f);
  }
}

__global__ void k_count(const int* __restrict__ ei, u32* __restrict__ Ac, int E) {
  int e = blockIdx.x * 256 + threadIdx.x;
  if (e < E) {
    int src = ei[e];
    int dst = ei[E + e];
    u32 idx = (u32)dst * KP + (u32)src;
    atomicAdd(&Ac[idx >> 1], 1u << ((idx & 1) * 16));
  }
}

__global__ void k_cvtA(uint4* __restrict__ A, int n) {
  int i = blockIdx.x * 256 + threadIdx.x;
  if (i < n) {
    uint4 v = A[i];
    A[i] = make_uint4(cvt2(v.x), cvt2(v.y), cvt2(v.z), cvt2(v.w));
  }
}

template<int LDK, int NKI, int EPI>
__global__ __launch_bounds__(256, 2) void k_gemm(
    const u16* __restrict__ A, const u16* __restrict__ B, float* __restrict__ dst) {
  __shared__ u16 lA[3][128 * 64];
  __shared__ u16 lB[3][64 * 64];
  gemm_phase<LDK, NKI, EPI>(A, B, dst, &lA[0][0], &lB[0][0]);
}

__global__ void k_red1(const float* __restrict__ P1, const float* __restrict__ bias,
                       u16* __restrict__ hT) {
  red1_body(blockIdx.x * 256 + threadIdx.x, P1, bias, hT);
}

__global__ void k_red2(const float* __restrict__ P2, float* __restrict__ out) {
  red2_body(blockIdx.x * 256 + threadIdx.x, P2, out);
}

extern "C" void kernel_launch(void* const* d_in, const int* in_sizes, int n_in,
                              void* d_out, int out_size, void* d_ws, size_t ws_size,
                              hipStream_t stream) {
  const float* x    = (const float*)d_in[0];
  const int*   ei   = (const int*)d_in[1];
  const float* w    = (const float*)d_in[2];
  const float* bias = (const float*)d_in[3];
  float* out = (float*)d_out;

  char* ws = (char*)d_ws;
  u16*   xb = (u16*)(ws + XB_OFF);
  u16*   wb = (u16*)(ws + WB_OFF);
  u16*   hT = (u16*)(ws + HT_OFF);
  u16*   Ac = (u16*)(ws + AC_OFF);
  float* P  = (float*)(ws + P_OFF);

  int E = in_sizes[1] / 2;  // 500000

  // Preferred: single cooperative dispatch (512 blocks = 2/CU by 72KB LDS).
  void* args[] = { (void*)&x, (void*)&ei, (void*)&w, (void*)&bias,
                   (void*)&xb, (void*)&wb, (void*)&hT, (void*)&Ac,
                   (void*)&P, (void*)&out, (void*)&E };
  hipError_t rc = hipLaunchCooperativeKernel((const void*)k_mega, dim3(512),
                                             dim3(256), args, 0, stream);
  if (rc != hipSuccess) {
    // Fallback: proven R8 7-kernel path (identical math).
    k_prep<<<dim3(PREP_BLK), dim3(256), 0, stream>>>(x, w, xb, wb, (float4*)Ac);
    k_count<<<dim3((E + 255) / 256), dim3(256), 0, stream>>>(ei, (u32*)Ac, E);
    k_cvtA<<<dim3(ZF4 / 256), dim3(256), 0, stream>>>((uint4*)Ac, ZF4);
    k_gemm<IN_C, IN_C / 2 / 64, 0><<<dim3(GEMM_BLK), dim3(256), 0, stream>>>(xb, wb, P);
    k_red1<<<dim3(OUT_C * MP / 8 / 256), dim3(256), 0, stream>>>(P, bias, hT);
    k_gemm<KP, KP / 2 / 64, 1><<<dim3(GEMM_BLK), dim3(256), 0, stream>>>(Ac, hT, P);
    k_red2<<<dim3(N_NODES * OUT_C / 4 / 256), dim3(256), 0, stream>>>(P, out);
  }
}

// Round 10
// 142.630 us; speedup vs baseline: 3.5770x; 3.5770x over previous
//
#include <hip/hip_runtime.h>
#include <stdint.h>

typedef unsigned short u16;
typedef unsigned int u32;

#define N_NODES 2708
#define IN_C    2048
#define OUT_C   512
#define MP      2816   // padded node count (multiple of 128)
#define KP      2816   // padded K for gemm2 (= MP)

using floatx4 = __attribute__((ext_vector_type(4))) float;
using short8  = __attribute__((ext_vector_type(8))) short;

// ---- workspace layout (43.9 MB used; ws_size = 256 MiB per WRITE_SIZE) ----
constexpr size_t XB_OFF = 0;
constexpr size_t XB_SZ  = (size_t)MP * IN_C * 2;      // 11,534,336
constexpr size_t WB_OFF = XB_OFF + XB_SZ;
constexpr size_t WB_SZ  = (size_t)OUT_C * IN_C * 2;   //  2,097,152
constexpr size_t HT_OFF = WB_OFF + WB_SZ;
constexpr size_t HT_SZ  = (size_t)OUT_C * MP * 2;     //  2,883,584
constexpr size_t AC_OFF = HT_OFF + HT_SZ;             // 16,515,072
constexpr size_t AC_SZ  = (size_t)MP * KP * 2;        // 15,859,712
constexpr size_t P_OFF  = AC_OFF + AC_SZ;             // 32,374,784
constexpr size_t P_SZ   = (size_t)2 * OUT_C * MP * 4; // 11,534,336 (P1/P2 share)

constexpr int ZF4 = (int)(AC_SZ / 16);                // 991,232
constexpr int GEMM_BLK = 704;                         // 8 bn x 44 bm x 2 ks

static __device__ __forceinline__ u16 f2bf(float f) {
  union { float f; u32 u; } v; v.f = f;
  u32 r = v.u + 0x7fffu + ((v.u >> 16) & 1u);  // RNE
  return (u16)(r >> 16);
}
static __device__ __forceinline__ u32 cvt2(u32 w) {
  float lo = (float)(w & 0xffffu), hi = (float)(w >> 16);
  return (u32)f2bf(lo) | ((u32)f2bf(hi) << 16);
}

// ---- fused prep: x -> bf16 (padded rows), w -> bf16, zero Ac ----
constexpr int XBLK = MP * IN_C / 8 / 256;              // 2816
constexpr int WBLK = OUT_C * IN_C / 8 / 256;           // 512
constexpr int ZBLK = ZF4 / 256;                        // 3872 (exact)
constexpr int PREP_BLK = XBLK + WBLK + ZBLK;           // 7200

__global__ void k_prep(const float* __restrict__ x, const float* __restrict__ w,
                       u16* __restrict__ xb, u16* __restrict__ wb,
                       float4* __restrict__ zac) {
  const int b = blockIdx.x, tid = threadIdx.x;
  if (b < XBLK) {
    const int i = b * 256 + tid;
    const int row = i >> 8, col = (i & 255) * 8;
    union { u16 u[8]; uint4 v; } o;
    if (row < N_NODES) {
      float4 v0 = *(const float4*)&x[(size_t)row * IN_C + col];
      float4 v1 = *(const float4*)&x[(size_t)row * IN_C + col + 4];
      o.u[0]=f2bf(v0.x); o.u[1]=f2bf(v0.y); o.u[2]=f2bf(v0.z); o.u[3]=f2bf(v0.w);
      o.u[4]=f2bf(v1.x); o.u[5]=f2bf(v1.y); o.u[6]=f2bf(v1.z); o.u[7]=f2bf(v1.w);
    } else {
      o.v = make_uint4(0, 0, 0, 0);
    }
    *(uint4*)&xb[(size_t)row * IN_C + col] = o.v;
  } else if (b < XBLK + WBLK) {
    const int idx = ((b - XBLK) * 256 + tid) * 8;
    float4 v0 = *(const float4*)&w[idx];
    float4 v1 = *(const float4*)&w[idx + 4];
    union { u16 u[8]; uint4 v; } o;
    o.u[0]=f2bf(v0.x); o.u[1]=f2bf(v0.y); o.u[2]=f2bf(v0.z); o.u[3]=f2bf(v0.w);
    o.u[4]=f2bf(v1.x); o.u[5]=f2bf(v1.y); o.u[6]=f2bf(v1.z); o.u[7]=f2bf(v1.w);
    *(uint4*)&wb[idx] = o.v;
  } else {
    zac[(b - XBLK - WBLK) * 256 + tid] = make_float4(0.f, 0.f, 0.f, 0.f);
  }
}

// ---- edge counts into u16 halfwords via u32 atomics ----
__global__ void k_count(const int* __restrict__ ei, u32* __restrict__ Ac, int E) {
  int e = blockIdx.x * 256 + threadIdx.x;
  if (e < E) {
    int src = ei[e];
    int dst = ei[E + e];
    u32 idx = (u32)dst * KP + (u32)src;  // u16 element index
    atomicAdd(&Ac[idx >> 1], 1u << ((idx & 1) * 16));
  }
}

// ---- in-place u16 count -> bf16 (exact for counts <= 256) ----
__global__ void k_cvtA(uint4* __restrict__ A, int n) {
  int i = blockIdx.x * 256 + threadIdx.x;
  if (i < n) {
    uint4 v = A[i];
    A[i] = make_uint4(cvt2(v.x), cvt2(v.y), cvt2(v.z), cvt2(v.w));
  }
}

// ---- GEMM: P[ks] partial of C[m][n] = sum_k A[m][k]*B[n][k], bf16, ld=LDK.
// BM=64 BN=64 BK=64, KS=2 (f32 partials, no atomics), 4 waves 2x2 (wave tile
// 32x32, acc[2][2]). Grid 704 (8 bn x 44 bm x 2 ks) = 2.75 blk/CU avg, LDS
// 3x16=48 KB -> 3 blk/CU capacity (all resident) -> ~11 waves/CU implicit
// overlap (m97/m114 mechanism -- the measured lever across R4-R8).
// R6-proven T4 loop: 3 buffers, STAGE 2 ahead, vmcnt(4) mid-loop (4 loads/
// stage/thread). T2 both-sides swizzle (rule #21), XCD-bijective swizzle
// (704 % 8 == 0), T5 setprio.
// EPI=0: dst = P1 f32 [KS][OUT_C][MP]; EPI=1: dst = P2 f32 [KS][MP][OUT_C].
template<int LDK, int NKI, int EPI>
__global__ __launch_bounds__(256, 3) void k_gemm(
    const u16* __restrict__ A, const u16* __restrict__ B, float* __restrict__ dst) {
  __shared__ u16 lA[3][64 * 64];
  __shared__ u16 lB[3][64 * 64];
  const int tid = threadIdx.x, lane = tid & 63, wid = tid >> 6;

  // XCD swizzle: 88 consecutive swz per XCD -> shared A/B panels L2-resident.
  const int cpx = (int)gridDim.x >> 3;          // 88
  const int orig = blockIdx.x;
  const int swz = (orig & 7) * cpx + (orig >> 3);
  const int bn = swz & 7;
  const int rest = swz >> 3;                    // 0..87
  const int ks = (rest >= 44) ? 1 : 0;
  const int bm = rest - ks * 44;
  const int bmr = bm * 64, bnr = bn * 64;
  const long k0b = (long)ks * LDK;              // K byte-offset (LDK/2 elems * 2B)

  const int wr = wid >> 1, wc = wid & 1;

  // staging: tile 64x64 bf16 = 8 KB = 8 chunks of 1 KB (8 rows each);
  // wave w -> chunks {w, w+4}; lane l -> row 8c+(l>>3), slot (l&7)^(row&7).
  const int swzl = ((lane & 7) ^ ((lane >> 3) & 7)) * 16;
  const char* ag[2];
  const char* bg[2];
#pragma unroll
  for (int j = 0; j < 2; ++j) {
    int c = wid + 4 * j, row = 8 * c + (lane >> 3);
    ag[j] = (const char*)A + (size_t)(bmr + row) * (LDK * 2) + k0b + swzl;
    bg[j] = (const char*)B + (size_t)(bnr + row) * (LDK * 2) + k0b + swzl;
  }

  // 4 global_load_lds per thread per STAGE (2 A + 2 B) -> vmcnt units of 4
#define STAGE(bb, tt) do {                                                        \
  _Pragma("unroll")                                                               \
  for (int j = 0; j < 2; ++j) {                                                   \
    __builtin_amdgcn_global_load_lds(                                             \
      (const __attribute__((address_space(1))) u32*)(ag[j] + (size_t)(tt) * 128), \
      (__attribute__((address_space(3))) u32*)&lA[bb][(wid + 4 * j) * 512],       \
      16, 0, 0);                                                                  \
    __builtin_amdgcn_global_load_lds(                                             \
      (const __attribute__((address_space(1))) u32*)(bg[j] + (size_t)(tt) * 128), \
      (__attribute__((address_space(3))) u32*)&lB[bb][(wid + 4 * j) * 512],       \
      16, 0, 0);                                                                  \
  }                                                                               \
} while (0)

  floatx4 acc[2][2] = {};

  STAGE(0, 0);
  if (NKI > 1) STAGE(1, 1);
  int cur = 0;
  for (int t = 0; t < NKI; ++t) {
    // wait for stage(t) only: leaves stage(t+1)'s 4 loads in flight
    if (t + 1 < NKI) asm volatile("s_waitcnt vmcnt(4)" ::: "memory");
    else             asm volatile("s_waitcnt vmcnt(0)" ::: "memory");
    __builtin_amdgcn_s_barrier();
    asm volatile("" ::: "memory");           // fence: keep ds_reads below barrier
    if (t + 2 < NKI) {
      int nb = cur + 2; if (nb >= 3) nb -= 3;
      STAGE(nb, t + 2);                      // overwrites buf consumed at t-1: safe
    }
    const u16* pA = lA[cur];
    const u16* pB = lB[cur];
    short8 af[2][2], bf[2][2];
    // read-side swizzle: slot' = slot ^ (row&7); row&7 == lane&7 for A and B.
#pragma unroll
    for (int mi = 0; mi < 2; ++mi)
#pragma unroll
      for (int kk = 0; kk < 2; ++kk) {
        const int row = wr * 32 + mi * 16 + (lane & 15);
        const int col8 = ((kk * 4 + (lane >> 4)) ^ (lane & 7)) * 8;
        af[mi][kk] = *(const short8*)&pA[row * 64 + col8];
      }
#pragma unroll
    for (int ni = 0; ni < 2; ++ni)
#pragma unroll
      for (int kk = 0; kk < 2; ++kk) {
        const int row = wc * 32 + ni * 16 + (lane & 15);
        const int col8 = ((kk * 4 + (lane >> 4)) ^ (lane & 7)) * 8;
        bf[ni][kk] = *(const short8*)&pB[row * 64 + col8];
      }
    __builtin_amdgcn_s_setprio(1);
#pragma unroll
    for (int kk = 0; kk < 2; ++kk)
#pragma unroll
      for (int mi = 0; mi < 2; ++mi)
#pragma unroll
        for (int ni = 0; ni < 2; ++ni)
          acc[mi][ni] = __builtin_amdgcn_mfma_f32_16x16x32_bf16(af[mi][kk], bf[ni][kk], acc[mi][ni], 0, 0, 0);
    __builtin_amdgcn_s_setprio(0);
    ++cur; if (cur >= 3) cur -= 3;
  }
#undef STAGE

  const int lr = (lane >> 4) * 4, lc = lane & 15;
  if (EPI == 0) {
    // P1[ks][n][m] f32, rows m contiguous -> float4 stores
#pragma unroll
    for (int ni = 0; ni < 2; ++ni) {
      const int n = bnr + wc * 32 + ni * 16 + lc;
#pragma unroll
      for (int mi = 0; mi < 2; ++mi) {
        const int m0 = bmr + wr * 32 + mi * 16 + lr;
        *(floatx4*)&dst[((size_t)ks * OUT_C + n) * MP + m0] = acc[mi][ni];
      }
    }
  } else {
    // P2[ks][m][n] f32 (padded rows; red2 ignores m >= N_NODES)
#pragma unroll
    for (int mi = 0; mi < 2; ++mi)
#pragma unroll
      for (int j = 0; j < 4; ++j) {
        const int m = bmr + wr * 32 + mi * 16 + lr + j;
#pragma unroll
        for (int ni = 0; ni < 2; ++ni) {
          const int n = bnr + wc * 32 + ni * 16 + lc;
          dst[((size_t)ks * MP + m) * OUT_C + n] = acc[mi][ni][j];
        }
      }
  }
}

// ---- red1: hT[n][m] = bf16(P1[0][n][m] + P1[1][n][m] + bias[n]) ----
__global__ void k_red1(const float* __restrict__ P1, const float* __restrict__ bias,
                       u16* __restrict__ hT) {
  int i8 = blockIdx.x * 256 + threadIdx.x;       // [0, OUT_C * MP/8)
  int n = i8 / (MP / 8);
  int m0 = (i8 - n * (MP / 8)) * 8;
  float bv = bias[n];
  const float* p0 = &P1[(size_t)n * MP + m0];
  const float* p1 = p0 + (size_t)OUT_C * MP;
  float4 a0 = *(const float4*)p0, a1 = *(const float4*)(p0 + 4);
  float4 b0 = *(const float4*)p1, b1 = *(const float4*)(p1 + 4);
  union { u16 u[8]; uint4 v; } o;
  o.u[0]=f2bf(a0.x+b0.x+bv); o.u[1]=f2bf(a0.y+b0.y+bv);
  o.u[2]=f2bf(a0.z+b0.z+bv); o.u[3]=f2bf(a0.w+b0.w+bv);
  o.u[4]=f2bf(a1.x+b1.x+bv); o.u[5]=f2bf(a1.y+b1.y+bv);
  o.u[6]=f2bf(a1.z+b1.z+bv); o.u[7]=f2bf(a1.w+b1.w+bv);
  *(uint4*)&hT[(size_t)n * MP + m0] = o.v;
}

// ---- red2: out[m][n] = P2[0][m][n] + P2[1][m][n], m < N_NODES ----
__global__ void k_red2(const float* __restrict__ P2, float* __restrict__ out) {
  int i = blockIdx.x * 256 + threadIdx.x;        // [0, N_NODES*OUT_C/4) exact
  size_t o = (size_t)i * 4;
  float4 a = *(const float4*)&P2[o];
  float4 b = *(const float4*)&P2[(size_t)MP * OUT_C + o];
  *(float4*)&out[o] = make_float4(a.x + b.x, a.y + b.y, a.z + b.z, a.w + b.w);
}

extern "C" void kernel_launch(void* const* d_in, const int* in_sizes, int n_in,
                              void* d_out, int out_size, void* d_ws, size_t ws_size,
                              hipStream_t stream) {
  const float* x    = (const float*)d_in[0];
  const int*   ei   = (const int*)d_in[1];
  const float* w    = (const float*)d_in[2];
  const float* bias = (const float*)d_in[3];
  float* out = (float*)d_out;

  char* ws = (char*)d_ws;
  u16*   xb = (u16*)(ws + XB_OFF);
  u16*   wb = (u16*)(ws + WB_OFF);
  u16*   hT = (u16*)(ws + HT_OFF);
  u16*   Ac = (u16*)(ws + AC_OFF);   // u16 counts, then bf16 in-place
  float* P  = (float*)(ws + P_OFF);  // P1 [2][512][2816] then P2 [2][2816][512]

  const int E = in_sizes[1] / 2;  // 500000

  k_prep<<<dim3(PREP_BLK), dim3(256), 0, stream>>>(x, w, xb, wb, (float4*)Ac);
  k_count<<<dim3((E + 255) / 256), dim3(256), 0, stream>>>(ei, (u32*)Ac, E);
  k_cvtA<<<dim3(ZF4 / 256), dim3(256), 0, stream>>>((uint4*)Ac, ZF4);
  // GEMM1 partials: P1[ks][n][m] = sum_{k in ks} xb[m][k]*wb[n][k]  (K=2048)
  k_gemm<IN_C, IN_C / 2 / 64, 0><<<dim3(GEMM_BLK), dim3(256), 0, stream>>>(xb, wb, P);
  k_red1<<<dim3(OUT_C * MP / 8 / 256), dim3(256), 0, stream>>>(P, bias, hT);
  // GEMM2 partials: P2[ks][m][n] = sum_{k in ks} Ac[m][k]*hT[n][k]  (K=2816)
  k_gemm<KP, KP / 2 / 64, 1><<<dim3(GEMM_BLK), dim3(256), 0, stream>>>(Ac, hT, P);
  k_red2<<<dim3(N_NODES * OUT_C / 4 / 256), dim3(256), 0, stream>>>(P, out);
}

// Round 11
// 136.401 us; speedup vs baseline: 3.7404x; 1.0457x over previous
//
#include <hip/hip_runtime.h>
#include <stdint.h>

typedef unsigned char  u8;
typedef unsigned short u16;
typedef unsigned int u32;

#define N_NODES 2708
#define IN_C    2048
#define OUT_C   512
#define MP      2816   // padded node count (multiple of 128)
#define KP      2816   // padded K for gemm2 (= MP)

using floatx4 = __attribute__((ext_vector_type(4))) float;
using short8  = __attribute__((ext_vector_type(8))) short;

// ---- workspace layout (51.8 MB used; ws is 256 MiB) ----
constexpr size_t XB_OFF  = 0;
constexpr size_t XB_SZ   = (size_t)MP * IN_C * 2;      // 11,534,336
constexpr size_t WB_OFF  = XB_OFF + XB_SZ;
constexpr size_t WB_SZ   = (size_t)OUT_C * IN_C * 2;   //  2,097,152
constexpr size_t HT_OFF  = WB_OFF + WB_SZ;
constexpr size_t HT_SZ   = (size_t)OUT_C * MP * 2;     //  2,883,584
constexpr size_t CNT_OFF = HT_OFF + HT_SZ;             // 16,515,072
constexpr size_t CNT_SZ  = (size_t)MP * KP;            //  7,929,856 (u8 counts)
constexpr size_t AB_OFF  = CNT_OFF + CNT_SZ;           // 24,444,928
constexpr size_t AB_SZ   = (size_t)MP * KP * 2;        // 15,859,712 (bf16 A)
constexpr size_t P_OFF   = AB_OFF + AB_SZ;             // 40,304,640
constexpr size_t P_SZ    = (size_t)2 * OUT_C * MP * 4; // 11,534,336 (P1/P2 share)

constexpr int GEMM_BLK = 704;                          // 8 bn x 44 bm x 2 ks
constexpr int CVT_I4   = (int)(CNT_SZ / 16);           // 495,616 uint4 reads
constexpr int CVT_BLK  = CVT_I4 / 256;                 // 1936 (exact)

static __device__ __forceinline__ u16 f2bf(float f) {
  union { float f; u32 u; } v; v.f = f;
  u32 r = v.u + 0x7fffu + ((v.u >> 16) & 1u);  // RNE
  return (u16)(r >> 16);
}

// ---- fused prep: x -> bf16 (padded rows), w -> bf16, zero Cnt (u8) ----
constexpr int XBLK = MP * IN_C / 8 / 256;              // 2816
constexpr int WBLK = OUT_C * IN_C / 8 / 256;           // 512
constexpr int ZBLK = CVT_I4 / 256;                     // 1936 (float4 = 16B)
constexpr int PREP_BLK = XBLK + WBLK + ZBLK;           // 5264

__global__ void k_prep(const float* __restrict__ x, const float* __restrict__ w,
                       u16* __restrict__ xb, u16* __restrict__ wb,
                       uint4* __restrict__ zcnt) {
  const int b = blockIdx.x, tid = threadIdx.x;
  if (b < XBLK) {
    const int i = b * 256 + tid;
    const int row = i >> 8, col = (i & 255) * 8;
    union { u16 u[8]; uint4 v; } o;
    if (row < N_NODES) {
      float4 v0 = *(const float4*)&x[(size_t)row * IN_C + col];
      float4 v1 = *(const float4*)&x[(size_t)row * IN_C + col + 4];
      o.u[0]=f2bf(v0.x); o.u[1]=f2bf(v0.y); o.u[2]=f2bf(v0.z); o.u[3]=f2bf(v0.w);
      o.u[4]=f2bf(v1.x); o.u[5]=f2bf(v1.y); o.u[6]=f2bf(v1.z); o.u[7]=f2bf(v1.w);
    } else {
      o.v = make_uint4(0, 0, 0, 0);
    }
    *(uint4*)&xb[(size_t)row * IN_C + col] = o.v;
  } else if (b < XBLK + WBLK) {
    const int idx = ((b - XBLK) * 256 + tid) * 8;
    float4 v0 = *(const float4*)&w[idx];
    float4 v1 = *(const float4*)&w[idx + 4];
    union { u16 u[8]; uint4 v; } o;
    o.u[0]=f2bf(v0.x); o.u[1]=f2bf(v0.y); o.u[2]=f2bf(v0.z); o.u[3]=f2bf(v0.w);
    o.u[4]=f2bf(v1.x); o.u[5]=f2bf(v1.y); o.u[6]=f2bf(v1.z); o.u[7]=f2bf(v1.w);
    *(uint4*)&wb[idx] = o.v;
  } else {
    zcnt[(b - XBLK - WBLK) * 256 + tid] = make_uint4(0, 0, 0, 0);
  }
}

// ---- edge counts into u8 byte lanes via u32 atomics (counts << 256) ----
__global__ void k_count(const int* __restrict__ ei, u32* __restrict__ Cnt, int E) {
  int e = blockIdx.x * 256 + threadIdx.x;
  if (e < E) {
    int src = ei[e];
    int dst = ei[E + e];
    u32 idx = (u32)dst * KP + (u32)src;  // u8 element index
    atomicAdd(&Cnt[idx >> 2], 1u << ((idx & 3) * 8));
  }
}

// ---- GEMM: P[ks] partial of C[m][n] = sum_k A[m][k]*B[n][k], bf16, ld=LDK.
// BM=64 BN=64 BK=64, KS=2 (f32 partials, no atomics), 4 waves 2x2 (wave tile
// 32x32, acc[2][2]). 704 gemm blocks (2.75 blk/CU avg, LDS 3x16=48 KB -> 3
// blk/CU capacity) -- R10-measured-best geometry. T4 loop: 3 buffers, STAGE
// 2 ahead, vmcnt(4) mid-loop. T2 both-sides swizzle (rule #21), XCD-bijective
// swizzle over the 704 gemm blocks, T5 setprio.
// FUSECVT: blocks >= GEMM_BLK instead convert Cnt u8 -> Ab bf16 (rides in the
// CU slots the gemm blocks leave free; both depend only on k_count, and the
// kernel boundary joins before gemm2 consumes Ab).
// EPI=0: dst = P1 f32 [KS][OUT_C][MP]; EPI=1: dst = P2 f32 [KS][MP][OUT_C].
template<int LDK, int NKI, int EPI, bool FUSECVT>
__global__ __launch_bounds__(256, 3) void k_gemm(
    const u16* __restrict__ A, const u16* __restrict__ B, float* __restrict__ dst,
    const uint4* __restrict__ Cnt, u16* __restrict__ Ab) {
  const int tid = threadIdx.x;
  if (FUSECVT && blockIdx.x >= GEMM_BLK) {
    const int i = (blockIdx.x - GEMM_BLK) * 256 + tid;   // [0, CVT_I4)
    uint4 v = Cnt[i];
    union { u16 u[16]; uint4 q[2]; } o;
    const u32 wv[4] = { v.x, v.y, v.z, v.w };
#pragma unroll
    for (int j = 0; j < 4; ++j)
#pragma unroll
      for (int bq = 0; bq < 4; ++bq)
        o.u[j * 4 + bq] = f2bf((float)((wv[j] >> (bq * 8)) & 0xffu));
    uint4* dstq = (uint4*)&Ab[(size_t)i * 16];
    dstq[0] = o.q[0];
    dstq[1] = o.q[1];
    return;
  }
  __shared__ u16 lA[3][64 * 64];
  __shared__ u16 lB[3][64 * 64];
  const int lane = tid & 63, wid = tid >> 6;

  // XCD swizzle over the 704 gemm blocks (dispatched first, round-robin):
  const int orig = blockIdx.x;
  const int swz = (orig & 7) * 88 + (orig >> 3);
  const int bn = swz & 7;
  const int rest = swz >> 3;                    // 0..87
  const int ks = (rest >= 44) ? 1 : 0;
  const int bm = rest - ks * 44;
  const int bmr = bm * 64, bnr = bn * 64;
  const long k0b = (long)ks * LDK;              // K byte-offset (LDK/2 elems * 2B)

  const int wr = wid >> 1, wc = wid & 1;

  // staging: tile 64x64 bf16 = 8 KB = 8 chunks of 1 KB (8 rows each);
  // wave w -> chunks {w, w+4}; lane l -> row 8c+(l>>3), slot (l&7)^(row&7).
  const int swzl = ((lane & 7) ^ ((lane >> 3) & 7)) * 16;
  const char* ag[2];
  const char* bg[2];
#pragma unroll
  for (int j = 0; j < 2; ++j) {
    int c = wid + 4 * j, row = 8 * c + (lane >> 3);
    ag[j] = (const char*)A + (size_t)(bmr + row) * (LDK * 2) + k0b + swzl;
    bg[j] = (const char*)B + (size_t)(bnr + row) * (LDK * 2) + k0b + swzl;
  }

  // 4 global_load_lds per thread per STAGE (2 A + 2 B) -> vmcnt units of 4
#define STAGE(bb, tt) do {                                                        \
  _Pragma("unroll")                                                               \
  for (int j = 0; j < 2; ++j) {                                                   \
    __builtin_amdgcn_global_load_lds(                                             \
      (const __attribute__((address_space(1))) u32*)(ag[j] + (size_t)(tt) * 128), \
      (__attribute__((address_space(3))) u32*)&lA[bb][(wid + 4 * j) * 512],       \
      16, 0, 0);                                                                  \
    __builtin_amdgcn_global_load_lds(                                             \
      (const __attribute__((address_space(1))) u32*)(bg[j] + (size_t)(tt) * 128), \
      (__attribute__((address_space(3))) u32*)&lB[bb][(wid + 4 * j) * 512],       \
      16, 0, 0);                                                                  \
  }                                                                               \
} while (0)

  floatx4 acc[2][2] = {};

  STAGE(0, 0);
  if (NKI > 1) STAGE(1, 1);
  int cur = 0;
  for (int t = 0; t < NKI; ++t) {
    // wait for stage(t) only: leaves stage(t+1)'s 4 loads in flight
    if (t + 1 < NKI) asm volatile("s_waitcnt vmcnt(4)" ::: "memory");
    else             asm volatile("s_waitcnt vmcnt(0)" ::: "memory");
    __builtin_amdgcn_s_barrier();
    asm volatile("" ::: "memory");           // fence: keep ds_reads below barrier
    if (t + 2 < NKI) {
      int nb = cur + 2; if (nb >= 3) nb -= 3;
      STAGE(nb, t + 2);                      // overwrites buf consumed at t-1: safe
    }
    const u16* pA = lA[cur];
    const u16* pB = lB[cur];
    short8 af[2][2], bf[2][2];
    // read-side swizzle: slot' = slot ^ (row&7); row&7 == lane&7 for A and B.
#pragma unroll
    for (int mi = 0; mi < 2; ++mi)
#pragma unroll
      for (int kk = 0; kk < 2; ++kk) {
        const int row = wr * 32 + mi * 16 + (lane & 15);
        const int col8 = ((kk * 4 + (lane >> 4)) ^ (lane & 7)) * 8;
        af[mi][kk] = *(const short8*)&pA[row * 64 + col8];
      }
#pragma unroll
    for (int ni = 0; ni < 2; ++ni)
#pragma unroll
      for (int kk = 0; kk < 2; ++kk) {
        const int row = wc * 32 + ni * 16 + (lane & 15);
        const int col8 = ((kk * 4 + (lane >> 4)) ^ (lane & 7)) * 8;
        bf[ni][kk] = *(const short8*)&pB[row * 64 + col8];
      }
    __builtin_amdgcn_s_setprio(1);
#pragma unroll
    for (int kk = 0; kk < 2; ++kk)
#pragma unroll
      for (int mi = 0; mi < 2; ++mi)
#pragma unroll
        for (int ni = 0; ni < 2; ++ni)
          acc[mi][ni] = __builtin_amdgcn_mfma_f32_16x16x32_bf16(af[mi][kk], bf[ni][kk], acc[mi][ni], 0, 0, 0);
    __builtin_amdgcn_s_setprio(0);
    ++cur; if (cur >= 3) cur -= 3;
  }
#undef STAGE

  const int lr = (lane >> 4) * 4, lc = lane & 15;
  if (EPI == 0) {
    // P1[ks][n][m] f32, rows m contiguous -> float4 stores
#pragma unroll
    for (int ni = 0; ni < 2; ++ni) {
      const int n = bnr + wc * 32 + ni * 16 + lc;
#pragma unroll
      for (int mi = 0; mi < 2; ++mi) {
        const int m0 = bmr + wr * 32 + mi * 16 + lr;
        *(floatx4*)&dst[((size_t)ks * OUT_C + n) * MP + m0] = acc[mi][ni];
      }
    }
  } else {
    // P2[ks][m][n] f32 (padded rows; red2 ignores m >= N_NODES)
#pragma unroll
    for (int mi = 0; mi < 2; ++mi)
#pragma unroll
      for (int j = 0; j < 4; ++j) {
        const int m = bmr + wr * 32 + mi * 16 + lr + j;
#pragma unroll
        for (int ni = 0; ni < 2; ++ni) {
          const int n = bnr + wc * 32 + ni * 16 + lc;
          dst[((size_t)ks * MP + m) * OUT_C + n] = acc[mi][ni][j];
        }
      }
  }
}

// ---- red1: hT[n][m] = bf16(P1[0][n][m] + P1[1][n][m] + bias[n]) ----
__global__ void k_red1(const float* __restrict__ P1, const float* __restrict__ bias,
                       u16* __restrict__ hT) {
  int i8 = blockIdx.x * 256 + threadIdx.x;       // [0, OUT_C * MP/8)
  int n = i8 / (MP / 8);
  int m0 = (i8 - n * (MP / 8)) * 8;
  float bv = bias[n];
  const float* p0 = &P1[(size_t)n * MP + m0];
  const float* p1 = p0 + (size_t)OUT_C * MP;
  float4 a0 = *(const float4*)p0, a1 = *(const float4*)(p0 + 4);
  float4 b0 = *(const float4*)p1, b1 = *(const float4*)(p1 + 4);
  union { u16 u[8]; uint4 v; } o;
  o.u[0]=f2bf(a0.x+b0.x+bv); o.u[1]=f2bf(a0.y+b0.y+bv);
  o.u[2]=f2bf(a0.z+b0.z+bv); o.u[3]=f2bf(a0.w+b0.w+bv);
  o.u[4]=f2bf(a1.x+b1.x+bv); o.u[5]=f2bf(a1.y+b1.y+bv);
  o.u[6]=f2bf(a1.z+b1.z+bv); o.u[7]=f2bf(a1.w+b1.w+bv);
  *(uint4*)&hT[(size_t)n * MP + m0] = o.v;
}

// ---- red2: out[m][n] = P2[0][m][n] + P2[1][m][n], m < N_NODES ----
__global__ void k_red2(const float* __restrict__ P2, float* __restrict__ out) {
  int i = blockIdx.x * 256 + threadIdx.x;        // [0, N_NODES*OUT_C/4) exact
  size_t o = (size_t)i * 4;
  float4 a = *(const float4*)&P2[o];
  float4 b = *(const float4*)&P2[(size_t)MP * OUT_C + o];
  *(float4*)&out[o] = make_float4(a.x + b.x, a.y + b.y, a.z + b.z, a.w + b.w);
}

extern "C" void kernel_launch(void* const* d_in, const int* in_sizes, int n_in,
                              void* d_out, int out_size, void* d_ws, size_t ws_size,
                              hipStream_t stream) {
  const float* x    = (const float*)d_in[0];
  const int*   ei   = (const int*)d_in[1];
  const float* w    = (const float*)d_in[2];
  const float* bias = (const float*)d_in[3];
  float* out = (float*)d_out;

  char* ws = (char*)d_ws;
  u16*   xb  = (u16*)(ws + XB_OFF);
  u16*   wb  = (u16*)(ws + WB_OFF);
  u16*   hT  = (u16*)(ws + HT_OFF);
  u8*    Cnt = (u8*)(ws + CNT_OFF);   // u8 edge counts
  u16*   Ab  = (u16*)(ws + AB_OFF);   // bf16 adjacency-count matrix
  float* P   = (float*)(ws + P_OFF);  // P1 [2][512][2816] then P2 [2][2816][512]

  const int E = in_sizes[1] / 2;  // 500000

  // prep: x->bf16(padded), w->bf16, zero Cnt
  k_prep<<<dim3(PREP_BLK), dim3(256), 0, stream>>>(x, w, xb, wb, (uint4*)Cnt);
  // edge counts (u8 byte-lane atomics)
  k_count<<<dim3((E + 255) / 256), dim3(256), 0, stream>>>(ei, (u32*)Cnt, E);
  // GEMM1 partials P1[ks][n][m] (K=2048) + fused Cnt->Ab bf16 convert
  k_gemm<IN_C, IN_C / 2 / 64, 0, true>
      <<<dim3(GEMM_BLK + CVT_BLK), dim3(256), 0, stream>>>(
          xb, wb, P, (const uint4*)Cnt, Ab);
  // reduce + bias -> hT bf16
  k_red1<<<dim3(OUT_C * MP / 8 / 256), dim3(256), 0, stream>>>(P, bias, hT);
  // GEMM2 partials P2[ks][m][n] (K=2816)
  k_gemm<KP, KP / 2 / 64, 1, false>
      <<<dim3(GEMM_BLK), dim3(256), 0, stream>>>(Ab, hT, P, nullptr, nullptr);
  // reduce -> out
  k_red2<<<dim3(N_NODES * OUT_C / 4 / 256), dim3(256), 0, stream>>>(P, out);
}

// Round 12
// 133.183 us; speedup vs baseline: 3.8307x; 1.0242x over previous
//
#include <hip/hip_runtime.h>
#include <stdint.h>

typedef unsigned char  u8;
typedef unsigned short u16;
typedef unsigned int u32;

#define N_NODES 2708
#define IN_C    2048
#define OUT_C   512
#define MP      2816   // padded node count (multiple of 128)
#define KP      2816   // padded K for gemm2 (= MP)

using floatx4 = __attribute__((ext_vector_type(4))) float;
using short8  = __attribute__((ext_vector_type(8))) short;

// ---- workspace layout (51.8 MB used; ws is 256 MiB) ----
constexpr size_t XB_OFF  = 0;
constexpr size_t XB_SZ   = (size_t)MP * IN_C * 2;      // 11,534,336
constexpr size_t WB_OFF  = XB_OFF + XB_SZ;
constexpr size_t WB_SZ   = (size_t)OUT_C * IN_C * 2;   //  2,097,152
constexpr size_t HT_OFF  = WB_OFF + WB_SZ;
constexpr size_t HT_SZ   = (size_t)OUT_C * MP * 2;     //  2,883,584
constexpr size_t CNT_OFF = HT_OFF + HT_SZ;             // 16,515,072
constexpr size_t CNT_SZ  = (size_t)MP * KP;            //  7,929,856 (u8 counts)
constexpr size_t AB_OFF  = CNT_OFF + CNT_SZ;           // 24,444,928
constexpr size_t AB_SZ   = (size_t)MP * KP * 2;        // 15,859,712 (bf16 A)
constexpr size_t P_OFF   = AB_OFF + AB_SZ;             // 40,304,640
constexpr size_t P_SZ    = (size_t)2 * MP * OUT_C * 4; // 11,534,336
// P region: P1b bf16 [2][OUT_C][MP] (5.8 MB) then reused as P2 f32 [2][MP][OUT_C]

constexpr int GEMM_BLK = 704;                          // 8 bn x 44 bm x 2 ks
constexpr int CVT_I4   = (int)(CNT_SZ / 16);           // 495,616 uint4 reads
constexpr int CVT_BLK  = CVT_I4 / 256;                 // 1936 (exact)

static __device__ __forceinline__ u16 f2bf(float f) {
  union { float f; u32 u; } v; v.f = f;
  u32 r = v.u + 0x7fffu + ((v.u >> 16) & 1u);  // RNE
  return (u16)(r >> 16);
}
static __device__ __forceinline__ float bf2f(u16 b) {
  union { u32 u; float f; } v; v.u = (u32)b << 16; return v.f;
}

// ---- zero Cnt (u8 counts; must precede the fire-and-forget atomics) ----
__global__ void k_zero(uint4* __restrict__ zcnt) {
  zcnt[blockIdx.x * 256 + threadIdx.x] = make_uint4(0, 0, 0, 0);
}

// ---- fused prep + count: issue edge atomic FIRST (fire-and-forget; latency
// hides under the streaming converts), then convert x/w -> bf16.
constexpr int XITEMS = MP * IN_C / 8;                  // 720,896
constexpr int WITEMS = OUT_C * IN_C / 8;               // 131,072
constexpr int PRECO_BLK = (XITEMS + WITEMS) / 256;     // 3328 (exact)

__global__ void k_preco(const float* __restrict__ x, const float* __restrict__ w,
                        const int* __restrict__ ei, u32* __restrict__ Cnt,
                        u16* __restrict__ xb, u16* __restrict__ wb, int E) {
  const int i = blockIdx.x * 256 + threadIdx.x;
  // edge atomic (first 500k threads): issue early, no result dependency
  if (i < E) {
    int src = ei[i];
    int dst = ei[E + i];
    u32 idx = (u32)dst * KP + (u32)src;  // u8 element index
    atomicAdd(&Cnt[idx >> 2], 1u << ((idx & 3) * 8));
  }
  if (i < XITEMS) {
    const int row = i >> 8, col = (i & 255) * 8;
    union { u16 u[8]; uint4 v; } o;
    if (row < N_NODES) {
      float4 v0 = *(const float4*)&x[(size_t)row * IN_C + col];
      float4 v1 = *(const float4*)&x[(size_t)row * IN_C + col + 4];
      o.u[0]=f2bf(v0.x); o.u[1]=f2bf(v0.y); o.u[2]=f2bf(v0.z); o.u[3]=f2bf(v0.w);
      o.u[4]=f2bf(v1.x); o.u[5]=f2bf(v1.y); o.u[6]=f2bf(v1.z); o.u[7]=f2bf(v1.w);
    } else {
      o.v = make_uint4(0, 0, 0, 0);
    }
    *(uint4*)&xb[(size_t)row * IN_C + col] = o.v;
  } else {
    const int idx = (i - XITEMS) * 8;
    float4 v0 = *(const float4*)&w[idx];
    float4 v1 = *(const float4*)&w[idx + 4];
    union { u16 u[8]; uint4 v; } o;
    o.u[0]=f2bf(v0.x); o.u[1]=f2bf(v0.y); o.u[2]=f2bf(v0.z); o.u[3]=f2bf(v0.w);
    o.u[4]=f2bf(v1.x); o.u[5]=f2bf(v1.y); o.u[6]=f2bf(v1.z); o.u[7]=f2bf(v1.w);
    *(uint4*)&wb[idx] = o.v;
  }
}

// ---- GEMM: P[ks] partial of C[m][n] = sum_k A[m][k]*B[n][k], bf16, ld=LDK.
// BM=64 BN=64 BK=64, KS=2, 4 waves 2x2 (wave tile 32x32, acc[2][2]).
// 704 gemm blocks (2.75 blk/CU, 3 blk/CU LDS capacity) -- R10/R11-proven.
// T4 loop (3 buf, STAGE 2 ahead, vmcnt(4) mid-loop), T2 both-sides swizzle,
// XCD-bijective swizzle, T5 setprio.
// FUSECVT: blocks >= GEMM_BLK convert Cnt u8 -> Ab bf16 (depend only on
// k_preco's atomics; kernel boundary joins before gemm2 reads Ab).
// EPI=0: dst = P1b bf16 [KS][OUT_C][MP] partials (uint2 stores).
// EPI=1: dst = P2 f32 [KS][MP][OUT_C] partials.
template<int LDK, int NKI, int EPI, bool FUSECVT>
__global__ __launch_bounds__(256, 3) void k_gemm(
    const u16* __restrict__ A, const u16* __restrict__ B, void* __restrict__ dst,
    const uint4* __restrict__ Cnt, u16* __restrict__ Ab) {
  const int tid = threadIdx.x;
  if (FUSECVT && blockIdx.x >= GEMM_BLK) {
    const int i = (blockIdx.x - GEMM_BLK) * 256 + tid;   // [0, CVT_I4)
    uint4 v = Cnt[i];
    union { u16 u[16]; uint4 q[2]; } o;
    const u32 wv[4] = { v.x, v.y, v.z, v.w };
#pragma unroll
    for (int j = 0; j < 4; ++j)
#pragma unroll
      for (int bq = 0; bq < 4; ++bq)
        o.u[j * 4 + bq] = f2bf((float)((wv[j] >> (bq * 8)) & 0xffu));
    uint4* dstq = (uint4*)&Ab[(size_t)i * 16];
    dstq[0] = o.q[0];
    dstq[1] = o.q[1];
    return;
  }
  __shared__ u16 lA[3][64 * 64];
  __shared__ u16 lB[3][64 * 64];
  const int lane = tid & 63, wid = tid >> 6;

  const int orig = blockIdx.x;
  const int swz = (orig & 7) * 88 + (orig >> 3);
  const int bn = swz & 7;
  const int rest = swz >> 3;                    // 0..87
  const int ks = (rest >= 44) ? 1 : 0;
  const int bm = rest - ks * 44;
  const int bmr = bm * 64, bnr = bn * 64;
  const long k0b = (long)ks * LDK;              // K byte-offset (LDK/2 elems * 2B)

  const int wr = wid >> 1, wc = wid & 1;

  const int swzl = ((lane & 7) ^ ((lane >> 3) & 7)) * 16;
  const char* ag[2];
  const char* bg[2];
#pragma unroll
  for (int j = 0; j < 2; ++j) {
    int c = wid + 4 * j, row = 8 * c + (lane >> 3);
    ag[j] = (const char*)A + (size_t)(bmr + row) * (LDK * 2) + k0b + swzl;
    bg[j] = (const char*)B + (size_t)(bnr + row) * (LDK * 2) + k0b + swzl;
  }

#define STAGE(bb, tt) do {                                                        \
  _Pragma("unroll")                                                               \
  for (int j = 0; j < 2; ++j) {                                                   \
    __builtin_amdgcn_global_load_lds(                                             \
      (const __attribute__((address_space(1))) u32*)(ag[j] + (size_t)(tt) * 128), \
      (__attribute__((address_space(3))) u32*)&lA[bb][(wid + 4 * j) * 512],       \
      16, 0, 0);                                                                  \
    __builtin_amdgcn_global_load_lds(                                             \
      (const __attribute__((address_space(1))) u32*)(bg[j] + (size_t)(tt) * 128), \
      (__attribute__((address_space(3))) u32*)&lB[bb][(wid + 4 * j) * 512],       \
      16, 0, 0);                                                                  \
  }                                                                               \
} while (0)

  floatx4 acc[2][2] = {};

  STAGE(0, 0);
  if (NKI > 1) STAGE(1, 1);
  int cur = 0;
  for (int t = 0; t < NKI; ++t) {
    if (t + 1 < NKI) asm volatile("s_waitcnt vmcnt(4)" ::: "memory");
    else             asm volatile("s_waitcnt vmcnt(0)" ::: "memory");
    __builtin_amdgcn_s_barrier();
    asm volatile("" ::: "memory");
    if (t + 2 < NKI) {
      int nb = cur + 2; if (nb >= 3) nb -= 3;
      STAGE(nb, t + 2);
    }
    const u16* pA = lA[cur];
    const u16* pB = lB[cur];
    short8 af[2][2], bf[2][2];
#pragma unroll
    for (int mi = 0; mi < 2; ++mi)
#pragma unroll
      for (int kk = 0; kk < 2; ++kk) {
        const int row = wr * 32 + mi * 16 + (lane & 15);
        const int col8 = ((kk * 4 + (lane >> 4)) ^ (lane & 7)) * 8;
        af[mi][kk] = *(const short8*)&pA[row * 64 + col8];
      }
#pragma unroll
    for (int ni = 0; ni < 2; ++ni)
#pragma unroll
      for (int kk = 0; kk < 2; ++kk) {
        const int row = wc * 32 + ni * 16 + (lane & 15);
        const int col8 = ((kk * 4 + (lane >> 4)) ^ (lane & 7)) * 8;
        bf[ni][kk] = *(const short8*)&pB[row * 64 + col8];
      }
    __builtin_amdgcn_s_setprio(1);
#pragma unroll
    for (int kk = 0; kk < 2; ++kk)
#pragma unroll
      for (int mi = 0; mi < 2; ++mi)
#pragma unroll
        for (int ni = 0; ni < 2; ++ni)
          acc[mi][ni] = __builtin_amdgcn_mfma_f32_16x16x32_bf16(af[mi][kk], bf[ni][kk], acc[mi][ni], 0, 0, 0);
    __builtin_amdgcn_s_setprio(0);
    ++cur; if (cur >= 3) cur -= 3;
  }
#undef STAGE

  const int lr = (lane >> 4) * 4, lc = lane & 15;
  if (EPI == 0) {
    // P1b[ks][n][m] bf16 partials, uint2 stores (4 x bf16)
    u16* p1 = (u16*)dst;
#pragma unroll
    for (int ni = 0; ni < 2; ++ni) {
      const int n = bnr + wc * 32 + ni * 16 + lc;
#pragma unroll
      for (int mi = 0; mi < 2; ++mi) {
        const int m0 = bmr + wr * 32 + mi * 16 + lr;
        union { u16 u[4]; uint2 v; } o;
#pragma unroll
        for (int j = 0; j < 4; ++j) o.u[j] = f2bf(acc[mi][ni][j]);
        *(uint2*)&p1[((size_t)ks * OUT_C + n) * MP + m0] = o.v;
      }
    }
  } else {
    float* p2 = (float*)dst;
#pragma unroll
    for (int mi = 0; mi < 2; ++mi)
#pragma unroll
      for (int j = 0; j < 4; ++j) {
        const int m = bmr + wr * 32 + mi * 16 + lr + j;
#pragma unroll
        for (int ni = 0; ni < 2; ++ni) {
          const int n = bnr + wc * 32 + ni * 16 + lc;
          p2[((size_t)ks * MP + m) * OUT_C + n] = acc[mi][ni][j];
        }
      }
  }
}

// ---- red1: hT[n][m] = bf16(P1b[0][n][m] + P1b[1][n][m] + bias[n]) ----
__global__ void k_red1(const u16* __restrict__ P1b, const float* __restrict__ bias,
                       u16* __restrict__ hT) {
  int i8 = blockIdx.x * 256 + threadIdx.x;       // [0, OUT_C * MP/8)
  int n = i8 / (MP / 8);
  int m0 = (i8 - n * (MP / 8)) * 8;
  float bv = bias[n];
  const u16* p0 = &P1b[(size_t)n * MP + m0];
  const u16* p1 = p0 + (size_t)OUT_C * MP;
  union { u16 u[8]; uint4 v; } a, b, o;
  a.v = *(const uint4*)p0;
  b.v = *(const uint4*)p1;
#pragma unroll
  for (int j = 0; j < 8; ++j) o.u[j] = f2bf(bf2f(a.u[j]) + bf2f(b.u[j]) + bv);
  *(uint4*)&hT[(size_t)n * MP + m0] = o.v;
}

// ---- red2: out[m][n] = P2[0][m][n] + P2[1][m][n], m < N_NODES ----
__global__ void k_red2(const float* __restrict__ P2, float* __restrict__ out) {
  int i = blockIdx.x * 256 + threadIdx.x;        // [0, N_NODES*OUT_C/4) exact
  size_t o = (size_t)i * 4;
  float4 a = *(const float4*)&P2[o];
  float4 b = *(const float4*)&P2[(size_t)MP * OUT_C + o];
  *(float4*)&out[o] = make_float4(a.x + b.x, a.y + b.y, a.z + b.z, a.w + b.w);
}

extern "C" void kernel_launch(void* const* d_in, const int* in_sizes, int n_in,
                              void* d_out, int out_size, void* d_ws, size_t ws_size,
                              hipStream_t stream) {
  const float* x    = (const float*)d_in[0];
  const int*   ei   = (const int*)d_in[1];
  const float* w    = (const float*)d_in[2];
  const float* bias = (const float*)d_in[3];
  float* out = (float*)d_out;

  char* ws = (char*)d_ws;
  u16*   xb  = (u16*)(ws + XB_OFF);
  u16*   wb  = (u16*)(ws + WB_OFF);
  u16*   hT  = (u16*)(ws + HT_OFF);
  u8*    Cnt = (u8*)(ws + CNT_OFF);   // u8 edge counts
  u16*   Ab  = (u16*)(ws + AB_OFF);   // bf16 adjacency-count matrix
  char*  P   = ws + P_OFF;            // P1b bf16 [2][512][2816] / P2 f32 [2][2816][512]

  const int E = in_sizes[1] / 2;  // 500000

  // zero Cnt (7.9 MB)
  k_zero<<<dim3(CVT_BLK), dim3(256), 0, stream>>>((uint4*)Cnt);
  // fused: edge-count atomics (fire-and-forget) + x/w -> bf16 converts
  k_preco<<<dim3(PRECO_BLK), dim3(256), 0, stream>>>(x, w, ei, (u32*)Cnt, xb, wb, E);
  // GEMM1 partials P1b[ks][n][m] bf16 (K=2048) + fused Cnt->Ab convert
  k_gemm<IN_C, IN_C / 2 / 64, 0, true>
      <<<dim3(GEMM_BLK + CVT_BLK), dim3(256), 0, stream>>>(
          xb, wb, P, (const uint4*)Cnt, Ab);
  // reduce + bias -> hT bf16
  k_red1<<<dim3(OUT_C * MP / 8 / 256), dim3(256), 0, stream>>>((const u16*)P, bias, hT);
  // GEMM2 partials P2[ks][m][n] f32 (K=2816)
  k_gemm<KP, KP / 2 / 64, 1, false>
      <<<dim3(GEMM_BLK), dim3(256), 0, stream>>>(Ab, hT, P, nullptr, nullptr);
  // reduce -> out
  k_red2<<<dim3(N_NODES * OUT_C / 4 / 256), dim3(256), 0, stream>>>((const float*)P, out);
}